// Round 2
// baseline (1080.334 us; speedup 1.0000x reference)
//
#include <hip/hip_runtime.h>

#define F 32
#define S 16

// ---------------------------------------------------------------------------
// Edge kernel: one thread per edge.
// msg[e,o] = sum_{s,f} ef[e,s] * x[src[e],f] * W[s, f*F+o]  + sum_f x[f]*B[f*F+o]
// scatter-add into agg[dst[e], :].
//
// CRITICAL: no divergent early-return — the whole compute body must be in
// uniform control flow so W/B loads are provably wave-uniform -> s_load
// (scalar cache). Divergence is confined to the trailing atomics.
// ---------------------------------------------------------------------------
__global__ __launch_bounds__(256, 2) void ecc_edge(
    const float* __restrict__ x,    // (N,F)
    const float* __restrict__ ef,   // (E,S)
    const int*   __restrict__ src,
    const int*   __restrict__ dst,
    const float* __restrict__ W,    // (S, F*F)
    const float* __restrict__ B,    // (F*F)
    float* __restrict__ agg,        // (N,F), pre-zeroed
    int E)
{
    const int tid   = blockIdx.x * blockDim.x + threadIdx.x;
    const bool live = (tid < E);
    const int  e    = live ? tid : (E - 1);   // clamp: keeps control flow uniform

    const int sn = src[e];
    const int dn = dst[e];

    // x[src] row into registers (vectorized)
    float xr[F];
    const float4* xp = (const float4*)(x + (size_t)sn * F);
    #pragma unroll
    for (int i = 0; i < F / 4; ++i) {
        float4 v = xp[i];
        xr[4*i+0] = v.x; xr[4*i+1] = v.y; xr[4*i+2] = v.z; xr[4*i+3] = v.w;
    }

    float acc[F];
    #pragma unroll
    for (int o = 0; o < F; ++o) acc[o] = 0.0f;

    const float* erow = ef + (size_t)e * S;
    for (int s = 0; s < S; ++s) {               // rolled: er[s] via per-lane L1 load
        const float es = erow[s];
        const float* Ws = W + s * (F * F);      // wave-uniform base
        #pragma unroll
        for (int f = 0; f < F; ++f) {           // FULL unroll: xr/acc stay in VGPRs
            const float z = es * xr[f];
            #pragma unroll
            for (int o = 0; o < F; ++o)
                acc[o] = fmaf(z, Ws[f * F + o], acc[o]);  // uniform -> s_load
        }
    }

    // fgn bias term: msg += sum_f x[f] * B[f*F+o]
    #pragma unroll
    for (int f = 0; f < F; ++f) {
        const float xf = xr[f];
        #pragma unroll
        for (int o = 0; o < F; ++o)
            acc[o] = fmaf(xf, B[f * F + o], acc[o]);
    }

    if (live) {
        float* ap = agg + (size_t)dn * F;
        #pragma unroll
        for (int o = 0; o < F; ++o)
            atomicAdd(ap + o, acc[o]);
    }
}

// ---------------------------------------------------------------------------
// Node kernel: h[n,o] = relu(agg[n,o] + bias[o] + sum_f x[n,f]*root[f,o])
// ---------------------------------------------------------------------------
__global__ __launch_bounds__(256) void ecc_node(
    const float* __restrict__ xin,   // (N,F)
    const float* __restrict__ root,  // (F,F)
    const float* __restrict__ bias,  // (F)
    float* __restrict__ h,           // (N,F): reads agg, writes relu'd h
    int N)
{
    int t = blockIdx.x * blockDim.x + threadIdx.x;
    if (t >= N * F) return;
    const int n = t >> 5;       // /F
    const int o = t & (F - 1);  // %F
    const float* xrow = xin + (size_t)n * F;
    float v = h[t] + bias[o];
    #pragma unroll
    for (int f = 0; f < F; ++f)
        v = fmaf(xrow[f], root[f * F + o], v);
    h[t] = fmaxf(v, 0.0f);
}

// ---------------------------------------------------------------------------
// Pool: pooled[c] = sum_n h[n,c]
// ---------------------------------------------------------------------------
__global__ __launch_bounds__(256) void pool_kernel(
    const float* __restrict__ h, float* __restrict__ pooled, int N)
{
    const int c = threadIdx.x & (F - 1);
    const int rowsPerBlock = 256 / F;  // 8
    float p = 0.0f;
    for (int n = blockIdx.x * rowsPerBlock + (threadIdx.x >> 5);
         n < N; n += gridDim.x * rowsPerBlock)
        p += h[(size_t)n * F + c];

    __shared__ float red[256];
    red[threadIdx.x] = p;
    __syncthreads();
    for (int off = 128; off >= F; off >>= 1) {
        if (threadIdx.x < off) red[threadIdx.x] += red[threadIdx.x + off];
        __syncthreads();
    }
    if (threadIdx.x < F) atomicAdd(&pooled[threadIdx.x], red[threadIdx.x]);
}

// ---------------------------------------------------------------------------
// Final: out[0] = sum_c pooled[c]*dense_w[c] + dense_b[0]
// ---------------------------------------------------------------------------
__global__ void final_kernel(
    const float* __restrict__ pooled,
    const float* __restrict__ dw,
    const float* __restrict__ db,
    float* __restrict__ out)
{
    const int o = threadIdx.x;  // one wave (64)
    float v = (o < F) ? pooled[o] * dw[o] : 0.0f;
    #pragma unroll
    for (int off = 32; off > 0; off >>= 1)
        v += __shfl_down(v, off, 64);
    if (o == 0) out[0] = v + db[0];
}

// ---------------------------------------------------------------------------
extern "C" void kernel_launch(void* const* d_in, const int* in_sizes, int n_in,
                              void* d_out, int out_size, void* d_ws, size_t ws_size,
                              hipStream_t stream) {
    const float* x      = (const float*)d_in[0];
    const float* efeat  = (const float*)d_in[1];
    const int*   src    = (const int*)d_in[2];
    const int*   dst    = (const int*)d_in[3];
    const float* fgn_w1 = (const float*)d_in[4];
    const float* fgn_b1 = (const float*)d_in[5];
    const float* root1  = (const float*)d_in[6];
    const float* bias1  = (const float*)d_in[7];
    const float* fgn_w2 = (const float*)d_in[8];
    const float* fgn_b2 = (const float*)d_in[9];
    const float* root2  = (const float*)d_in[10];
    const float* bias2  = (const float*)d_in[11];
    const float* dense_w = (const float*)d_in[12];
    const float* dense_b = (const float*)d_in[13];

    const int N = in_sizes[0] / F;
    const int E = in_sizes[2];

    // workspace: agg1 (N*F) | agg2 (N*F) | pooled (F)
    float* agg1   = (float*)d_ws;
    float* agg2   = agg1 + (size_t)N * F;
    float* pooled = agg2 + (size_t)N * F;

    hipMemsetAsync(d_ws, 0, ((size_t)2 * N * F + F) * sizeof(float), stream);

    const int edgeBlocks = (E + 255) / 256;
    const int nodeBlocks = (N * F + 255) / 256;

    // ---- layer 1 ----
    ecc_edge<<<edgeBlocks, 256, 0, stream>>>(x, efeat, src, dst, fgn_w1, fgn_b1, agg1, E);
    ecc_node<<<nodeBlocks, 256, 0, stream>>>(x, root1, bias1, agg1, N);   // agg1 -> h1

    // ---- layer 2 ----
    ecc_edge<<<edgeBlocks, 256, 0, stream>>>(agg1, efeat, src, dst, fgn_w2, fgn_b2, agg2, E);
    ecc_node<<<nodeBlocks, 256, 0, stream>>>(agg1, root2, bias2, agg2, N); // agg2 -> h2

    // ---- pool + dense ----
    pool_kernel<<<512, 256, 0, stream>>>(agg2, pooled, N);
    final_kernel<<<1, 64, 0, stream>>>(pooled, dense_w, dense_b, (float*)d_out);
}

// Round 3
// 381.386 us; speedup vs baseline: 2.8327x; 2.8327x over previous
//
#include <hip/hip_runtime.h>
#include <hip/hip_bf16.h>

#define F 32
#define S 16
#define SLICES 18  // slices 0..15 = fgn_w rows, 16 = fgn_b, 17 = root

__device__ __forceinline__ float bf_lo(unsigned u) { return __uint_as_float(u << 16); }
__device__ __forceinline__ float bf_hi(unsigned u) { return __uint_as_float(u & 0xffff0000u); }
__device__ __forceinline__ unsigned short f2bf(float f) {
    __hip_bfloat16 h = __float2bfloat16(f);  // RNE
    return *(unsigned short*)&h;
}

// ---------------------------------------------------------------------------
// Y precompute: Y[n, s, o] = sum_f in[n,f] * Wslice_s[f*F+o], bf16 storage.
// Thread = (s, o-pair) x 2 node-streams; W column pair lives in 64 VGPRs and
// is reused across ~50 nodes; x row loads are wave-broadcast (L1).
// ---------------------------------------------------------------------------
__global__ __launch_bounds__(576, 2) void precompute_y(
    const float* __restrict__ in,    // (N,F)
    const float* __restrict__ fgnw,  // (S, F*F)
    const float* __restrict__ fgnb,  // (F*F)
    const float* __restrict__ root,  // (F*F)
    unsigned* __restrict__ Yu,       // (N, SLICES, F/2) bf16-pairs
    int N)
{
    const int r  = threadIdx.x % 288;   // 288 = 18 slices * 16 o-pairs
    const int ns = threadIdx.x / 288;   // 2 node streams per block
    const int o2 = r & 15;
    const int s  = r >> 4;              // 0..17
    const float* Ws = (s < S) ? (fgnw + s * (F * F)) : ((s == S) ? fgnb : root);

    float w0[F], w1[F];
    #pragma unroll
    for (int f = 0; f < F; ++f) {
        float2 w = *(const float2*)(Ws + f * F + 2 * o2);
        w0[f] = w.x; w1[f] = w.y;
    }

    for (int n = blockIdx.x * 2 + ns; n < N; n += gridDim.x * 2) {
        const float4* xp = (const float4*)(in + (size_t)n * F);
        float a0 = 0.f, a1 = 0.f;
        #pragma unroll
        for (int i = 0; i < F / 4; ++i) {
            float4 v = xp[i];
            a0 = fmaf(v.x, w0[4*i+0], a0); a1 = fmaf(v.x, w1[4*i+0], a1);
            a0 = fmaf(v.y, w0[4*i+1], a0); a1 = fmaf(v.y, w1[4*i+1], a1);
            a0 = fmaf(v.z, w0[4*i+2], a0); a1 = fmaf(v.z, w1[4*i+2], a1);
            a0 = fmaf(v.w, w0[4*i+3], a0); a1 = fmaf(v.w, w1[4*i+3], a1);
        }
        unsigned up = (unsigned)f2bf(a0) | ((unsigned)f2bf(a1) << 16);
        Yu[((size_t)n * SLICES + s) * (F / 2) + o2] = up;
    }
}

// ---------------------------------------------------------------------------
// Edge gather: msg[e,o] = Y[src,16,o] + sum_{s<16} ef[e,s]*Y[src,s,o];
// lane = (edge, o-pair): 17 coalesced 64B line reads per edge, 2 coalesced
// atomics per lane (whole agg row dirtied as one 128B line, not 32 sectors).
// ---------------------------------------------------------------------------
__global__ __launch_bounds__(256) void edge_gather(
    const unsigned* __restrict__ Yu,  // (N, SLICES, F/2)
    const float* __restrict__ ef,     // (E,S)
    const int* __restrict__ src,
    const int* __restrict__ dst,
    float* __restrict__ agg,          // (N,F), pre-zeroed
    int E)
{
    const int gid = blockIdx.x * blockDim.x + threadIdx.x;
    const int e = gid >> 4;
    if (e >= E) return;
    const int o2 = gid & 15;
    const int sn = src[e], dn = dst[e];

    const unsigned* Yr = Yu + (size_t)sn * (SLICES * (F / 2)) + o2;
    const float4* efv = (const float4*)(ef + (size_t)e * S);
    float4 c0 = efv[0], c1 = efv[1], c2 = efv[2], c3 = efv[3];
    const float cs[S] = {c0.x, c0.y, c0.z, c0.w, c1.x, c1.y, c1.z, c1.w,
                         c2.x, c2.y, c2.z, c2.w, c3.x, c3.y, c3.z, c3.w};

    unsigned u = Yr[S * (F / 2)];  // slice 16 = fgn bias term (coeff 1)
    float m0 = bf_lo(u), m1 = bf_hi(u);
    #pragma unroll
    for (int s = 0; s < S; ++s) {
        unsigned v = Yr[s * (F / 2)];
        m0 = fmaf(cs[s], bf_lo(v), m0);
        m1 = fmaf(cs[s], bf_hi(v), m1);
    }
    float* ap = agg + (size_t)dn * F + 2 * o2;
    atomicAdd(ap,     m0);
    atomicAdd(ap + 1, m1);
}

// ---------------------------------------------------------------------------
// Node fuse: h[n,o] = relu(agg[n,o] + Y[n,17,o] + bias[o])   (slice 17 = x@root)
// ---------------------------------------------------------------------------
__global__ __launch_bounds__(256) void node_fuse(
    const unsigned short* __restrict__ Yb,  // bf16 view of Y
    const float* __restrict__ bias,
    float* __restrict__ h,  // in: agg, out: relu'd h (in-place)
    int N)
{
    const int t = blockIdx.x * blockDim.x + threadIdx.x;
    if (t >= N * F) return;
    const int n = t >> 5, o = t & (F - 1);
    const float rt = __uint_as_float(((unsigned)Yb[((size_t)n * SLICES + 17) * F + o]) << 16);
    h[t] = fmaxf(h[t] + rt + bias[o], 0.f);
}

// ---------------------------------------------------------------------------
// Fallback (ws too small): previous passing implementation.
// ---------------------------------------------------------------------------
__global__ __launch_bounds__(256, 2) void ecc_edge_slow(
    const float* __restrict__ x, const float* __restrict__ ef,
    const int* __restrict__ src, const int* __restrict__ dst,
    const float* __restrict__ W, const float* __restrict__ B,
    float* __restrict__ agg, int E)
{
    const int tid = blockIdx.x * blockDim.x + threadIdx.x;
    const bool live = (tid < E);
    const int e = live ? tid : (E - 1);
    const int sn = src[e], dn = dst[e];
    float xr[F];
    const float4* xp = (const float4*)(x + (size_t)sn * F);
    #pragma unroll
    for (int i = 0; i < F / 4; ++i) {
        float4 v = xp[i];
        xr[4*i+0] = v.x; xr[4*i+1] = v.y; xr[4*i+2] = v.z; xr[4*i+3] = v.w;
    }
    float acc[F];
    #pragma unroll
    for (int o = 0; o < F; ++o) acc[o] = 0.0f;
    const float* erow = ef + (size_t)e * S;
    for (int s = 0; s < S; ++s) {
        const float es = erow[s];
        const float* Ws = W + s * (F * F);
        #pragma unroll
        for (int f = 0; f < F; ++f) {
            const float z = es * xr[f];
            #pragma unroll
            for (int o = 0; o < F; ++o) acc[o] = fmaf(z, Ws[f * F + o], acc[o]);
        }
    }
    #pragma unroll
    for (int f = 0; f < F; ++f) {
        const float xf = xr[f];
        #pragma unroll
        for (int o = 0; o < F; ++o) acc[o] = fmaf(xf, B[f * F + o], acc[o]);
    }
    if (live) {
        float* ap = agg + (size_t)dn * F;
        #pragma unroll
        for (int o = 0; o < F; ++o) atomicAdd(ap + o, acc[o]);
    }
}

__global__ __launch_bounds__(256) void ecc_node_slow(
    const float* __restrict__ xin, const float* __restrict__ root,
    const float* __restrict__ bias, float* __restrict__ h, int N)
{
    int t = blockIdx.x * blockDim.x + threadIdx.x;
    if (t >= N * F) return;
    const int n = t >> 5, o = t & (F - 1);
    const float* xrow = xin + (size_t)n * F;
    float v = h[t] + bias[o];
    #pragma unroll
    for (int f = 0; f < F; ++f) v = fmaf(xrow[f], root[f * F + o], v);
    h[t] = fmaxf(v, 0.0f);
}

// ---------------------------------------------------------------------------
__global__ __launch_bounds__(256) void pool_kernel(
    const float* __restrict__ h, float* __restrict__ pooled, int N)
{
    const int c = threadIdx.x & (F - 1);
    const int rowsPerBlock = 256 / F;
    float p = 0.0f;
    for (int n = blockIdx.x * rowsPerBlock + (threadIdx.x >> 5);
         n < N; n += gridDim.x * rowsPerBlock)
        p += h[(size_t)n * F + c];
    __shared__ float red[256];
    red[threadIdx.x] = p;
    __syncthreads();
    for (int off = 128; off >= F; off >>= 1) {
        if (threadIdx.x < off) red[threadIdx.x] += red[threadIdx.x + off];
        __syncthreads();
    }
    if (threadIdx.x < F) atomicAdd(&pooled[threadIdx.x], red[threadIdx.x]);
}

__global__ void final_kernel(
    const float* __restrict__ pooled, const float* __restrict__ dw,
    const float* __restrict__ db, float* __restrict__ out)
{
    const int o = threadIdx.x;
    float v = (o < F) ? pooled[o] * dw[o] : 0.0f;
    #pragma unroll
    for (int off = 32; off > 0; off >>= 1) v += __shfl_down(v, off, 64);
    if (o == 0) out[0] = v + db[0];
}

// ---------------------------------------------------------------------------
extern "C" void kernel_launch(void* const* d_in, const int* in_sizes, int n_in,
                              void* d_out, int out_size, void* d_ws, size_t ws_size,
                              hipStream_t stream) {
    const float* x      = (const float*)d_in[0];
    const float* efeat  = (const float*)d_in[1];
    const int*   src    = (const int*)d_in[2];
    const int*   dst    = (const int*)d_in[3];
    const float* fgn_w1 = (const float*)d_in[4];
    const float* fgn_b1 = (const float*)d_in[5];
    const float* root1  = (const float*)d_in[6];
    const float* bias1  = (const float*)d_in[7];
    const float* fgn_w2 = (const float*)d_in[8];
    const float* fgn_b2 = (const float*)d_in[9];
    const float* root2  = (const float*)d_in[10];
    const float* bias2  = (const float*)d_in[11];
    const float* dense_w = (const float*)d_in[12];
    const float* dense_b = (const float*)d_in[13];

    const int N = in_sizes[0] / F;
    const int E = in_sizes[2];

    const size_t Ybytes   = (size_t)N * SLICES * F * 2;          // bf16 Y
    const size_t aggBytes = (size_t)N * F * sizeof(float);
    const size_t need     = Ybytes + 2 * aggBytes + 256;

    if (ws_size >= need) {
        unsigned*       Yu = (unsigned*)d_ws;
        unsigned short* Yb = (unsigned short*)d_ws;
        float* agg1   = (float*)((char*)d_ws + Ybytes);
        float* agg2   = agg1 + (size_t)N * F;
        float* pooled = agg2 + (size_t)N * F;

        hipMemsetAsync((char*)d_ws + Ybytes, 0, 2 * aggBytes + F * sizeof(float), stream);

        const int edgeBlocks = (E * (F / 2) + 255) / 256;
        const int nodeBlocks = (N * F + 255) / 256;

        // ---- layer 1 ----
        precompute_y<<<512, 576, 0, stream>>>(x, fgn_w1, fgn_b1, root1, Yu, N);
        edge_gather<<<edgeBlocks, 256, 0, stream>>>(Yu, efeat, src, dst, agg1, E);
        node_fuse<<<nodeBlocks, 256, 0, stream>>>(Yb, bias1, agg1, N);  // agg1 -> h1

        // ---- layer 2 ----
        precompute_y<<<512, 576, 0, stream>>>(agg1, fgn_w2, fgn_b2, root2, Yu, N);
        edge_gather<<<edgeBlocks, 256, 0, stream>>>(Yu, efeat, src, dst, agg2, E);
        node_fuse<<<nodeBlocks, 256, 0, stream>>>(Yb, bias2, agg2, N);  // agg2 -> h2

        pool_kernel<<<512, 256, 0, stream>>>(agg2, pooled, N);
        final_kernel<<<1, 64, 0, stream>>>(pooled, dense_w, dense_b, (float*)d_out);
    } else {
        // fallback: round-1 passing path (ws too small for Y)
        float* agg1   = (float*)d_ws;
        float* agg2   = agg1 + (size_t)N * F;
        float* pooled = agg2 + (size_t)N * F;
        hipMemsetAsync(d_ws, 0, 2 * aggBytes + F * sizeof(float), stream);
        const int edgeBlocks = (E + 255) / 256;
        const int nodeBlocks = (N * F + 255) / 256;
        ecc_edge_slow<<<edgeBlocks, 256, 0, stream>>>(x, efeat, src, dst, fgn_w1, fgn_b1, agg1, E);
        ecc_node_slow<<<nodeBlocks, 256, 0, stream>>>(x, root1, bias1, agg1, N);
        ecc_edge_slow<<<edgeBlocks, 256, 0, stream>>>(agg1, efeat, src, dst, fgn_w2, fgn_b2, agg2, E);
        ecc_node_slow<<<nodeBlocks, 256, 0, stream>>>(agg1, root2, bias2, agg2, N);
        pool_kernel<<<512, 256, 0, stream>>>(agg2, pooled, N);
        final_kernel<<<1, 64, 0, stream>>>(pooled, dense_w, dense_b, (float*)d_out);
    }
}

// Round 4
// 239.934 us; speedup vs baseline: 4.5026x; 1.5895x over previous
//
#include <hip/hip_runtime.h>
#include <hip/hip_bf16.h>

#define F 32
#define S 16
#define SLICES 18   // 0..15 = fgn_w rows, 16 = fgn_b, 17 = root
#define J (SLICES * F)  // 576 output columns of Y

typedef short v8s __attribute__((ext_vector_type(8)));
typedef float v4f __attribute__((ext_vector_type(4)));

__device__ __forceinline__ float bf_lo(unsigned u) { return __uint_as_float(u << 16); }
__device__ __forceinline__ float bf_hi(unsigned u) { return __uint_as_float(u & 0xffff0000u); }
__device__ __forceinline__ unsigned short f2bf(float f) {
    __hip_bfloat16 h = __float2bfloat16(f);  // RNE
    return *(unsigned short*)&h;
}

// ---------------------------------------------------------------------------
// Pack both layers' weights into bf16 Wbt[j][k]:  j = s*32+o (0..575), k = f.
// Wbt[j*32+k] = slice_s[k*32+o]   (slice 16 = fgn_b, 17 = root)
// ---------------------------------------------------------------------------
__global__ __launch_bounds__(256) void convert_w(
    const float* __restrict__ w1, const float* __restrict__ b1, const float* __restrict__ r1,
    const float* __restrict__ w2, const float* __restrict__ b2, const float* __restrict__ r2,
    unsigned short* __restrict__ Wbt1, unsigned short* __restrict__ Wbt2)
{
    int tid = blockIdx.x * blockDim.x + threadIdx.x;
    if (tid >= 2 * J * F) return;
    const int layer = tid / (J * F);
    const int rem   = tid % (J * F);
    const int j = rem >> 5;        // /32
    const int k = rem & 31;
    const int s = j >> 5;
    const int o = j & 31;
    const float* w = layer ? w2 : w1;
    const float* b = layer ? b2 : b1;
    const float* r = layer ? r2 : r1;
    const float* slice = (s < S) ? (w + s * (F * F)) : ((s == S) ? b : r);
    unsigned short* dst = layer ? Wbt2 : Wbt1;
    dst[j * F + k] = f2bf(slice[k * F + o]);
}

// ---------------------------------------------------------------------------
// Y GEMM via MFMA:  Y[n, j] = sum_k in[n,k] * Wbt[j][k],  bf16 out.
// Block = 64 nodes; LDS holds full B (576x32 bf16, j-major) + A tile (64x32).
// Wave w computes nodes n0+16w..+15; one mfma_f32_16x16x32_bf16 per 16-j tile.
// ---------------------------------------------------------------------------
__global__ __launch_bounds__(256) void y_gemm(
    const float* __restrict__ in,           // (N,F) fp32
    const unsigned short* __restrict__ Wbt, // (J,F) bf16
    unsigned short* __restrict__ Y,         // (N,J) bf16
    int N)
{
    __shared__ unsigned short Bs[J * F];    // 36864 B
    __shared__ unsigned short As[64 * F];   // 4096 B
    const int tid = threadIdx.x;
    const int n0  = blockIdx.x * 64;

    // stage B: 2304 uint4, 9 per thread
    {
        const uint4* s = (const uint4*)Wbt;
        uint4* d = (uint4*)Bs;
        #pragma unroll
        for (int i = 0; i < 9; ++i)
            d[tid + 256 * i] = s[tid + 256 * i];
    }
    // stage A: 8 bf16 per thread (node nl, f0..f0+7), fp32 -> bf16
    {
        const int idx = tid * 8;
        const int nl  = idx >> 5;
        const int f0  = idx & 31;
        int n = n0 + nl; if (n > N - 1) n = N - 1;
        const float4* xp = (const float4*)(in + (size_t)n * F + f0);
        float4 v0 = xp[0], v1 = xp[1];
        uint4 pk;
        pk.x = (unsigned)f2bf(v0.x) | ((unsigned)f2bf(v0.y) << 16);
        pk.y = (unsigned)f2bf(v0.z) | ((unsigned)f2bf(v0.w) << 16);
        pk.z = (unsigned)f2bf(v1.x) | ((unsigned)f2bf(v1.y) << 16);
        pk.w = (unsigned)f2bf(v1.z) | ((unsigned)f2bf(v1.w) << 16);
        *(uint4*)(As + idx) = pk;
    }
    __syncthreads();

    const int w    = tid >> 6;       // wave 0..3
    const int lane = tid & 63;
    const int lid  = lane & 15;
    const int quad = lane >> 4;

    // A fragment: A[m=lane&15][k=quad*8+j]  — same for all 36 j-tiles
    const v8s af = *(const v8s*)(As + ((w * 16 + lid) * F + quad * 8));

    #pragma unroll 4
    for (int jt = 0; jt < J / 16; ++jt) {
        // B fragment: B[k=quad*8+j][col=lane&15] from j-major Bs
        const v8s bf = *(const v8s*)(Bs + ((jt * 16 + lid) * F + quad * 8));
        v4f d = {0.f, 0.f, 0.f, 0.f};
        d = __builtin_amdgcn_mfma_f32_16x16x32_bf16(af, bf, d, 0, 0, 0);
        // D: col = lane&15 (j), row = quad*4 + reg (node)
        #pragma unroll
        for (int r = 0; r < 4; ++r) {
            const int n = n0 + w * 16 + quad * 4 + r;
            if (n < N)
                Y[(size_t)n * J + jt * 16 + lid] = f2bf(d[r]);
        }
    }
}

// ---------------------------------------------------------------------------
// Edge gather: msg[e,o] = Y[src,16,o] + sum_{s<16} ef[e,s]*Y[src,s,o]
// lane = (edge, o-pair); scatter-add to agg[dst].
// ---------------------------------------------------------------------------
__global__ __launch_bounds__(256) void edge_gather(
    const unsigned* __restrict__ Yu,  // (N, J/2) bf16-pairs
    const float* __restrict__ ef,     // (E,S)
    const int* __restrict__ src,
    const int* __restrict__ dst,
    float* __restrict__ agg,          // (N,F), pre-zeroed
    int E)
{
    const int gid = blockIdx.x * blockDim.x + threadIdx.x;
    const int e = gid >> 4;
    if (e >= E) return;
    const int o2 = gid & 15;
    const int sn = src[e], dn = dst[e];

    const unsigned* Yr = Yu + (size_t)sn * (J / 2) + o2;
    const float4* efv = (const float4*)(ef + (size_t)e * S);
    float4 c0 = efv[0], c1 = efv[1], c2 = efv[2], c3 = efv[3];
    const float cs[S] = {c0.x, c0.y, c0.z, c0.w, c1.x, c1.y, c1.z, c1.w,
                         c2.x, c2.y, c2.z, c2.w, c3.x, c3.y, c3.z, c3.w};

    unsigned u = Yr[S * (F / 2)];  // slice 16 = fgn bias term
    float m0 = bf_lo(u), m1 = bf_hi(u);
    #pragma unroll
    for (int s = 0; s < S; ++s) {
        unsigned v = Yr[s * (F / 2)];
        m0 = fmaf(cs[s], bf_lo(v), m0);
        m1 = fmaf(cs[s], bf_hi(v), m1);
    }
    float* ap = agg + (size_t)dn * F + 2 * o2;
    atomicAdd(ap,     m0);
    atomicAdd(ap + 1, m1);
}

// ---------------------------------------------------------------------------
// Node fuse: h[n,o] = relu(agg[n,o] + Y[n, slice17, o] + bias[o])
// ---------------------------------------------------------------------------
__global__ __launch_bounds__(256) void node_fuse(
    const unsigned short* __restrict__ Yb,
    const float* __restrict__ bias,
    float* __restrict__ h,  // in: agg, out: relu'd h (in-place)
    int N)
{
    const int t = blockIdx.x * blockDim.x + threadIdx.x;
    if (t >= N * F) return;
    const int n = t >> 5, o = t & (F - 1);
    const float rt = __uint_as_float(((unsigned)Yb[(size_t)n * J + 17 * F + o]) << 16);
    h[t] = fmaxf(h[t] + rt + bias[o], 0.f);
}

// ---------------------------------------------------------------------------
__global__ __launch_bounds__(256) void pool_kernel(
    const float* __restrict__ h, float* __restrict__ pooled, int N)
{
    const int c = threadIdx.x & (F - 1);
    const int rowsPerBlock = 256 / F;
    float p = 0.0f;
    for (int n = blockIdx.x * rowsPerBlock + (threadIdx.x >> 5);
         n < N; n += gridDim.x * rowsPerBlock)
        p += h[(size_t)n * F + c];
    __shared__ float red[256];
    red[threadIdx.x] = p;
    __syncthreads();
    for (int off = 128; off >= F; off >>= 1) {
        if (threadIdx.x < off) red[threadIdx.x] += red[threadIdx.x + off];
        __syncthreads();
    }
    if (threadIdx.x < F) atomicAdd(&pooled[threadIdx.x], red[threadIdx.x]);
}

__global__ void final_kernel(
    const float* __restrict__ pooled, const float* __restrict__ dw,
    const float* __restrict__ db, float* __restrict__ out)
{
    const int o = threadIdx.x;
    float v = (o < F) ? pooled[o] * dw[o] : 0.0f;
    #pragma unroll
    for (int off = 32; off > 0; off >>= 1) v += __shfl_down(v, off, 64);
    if (o == 0) out[0] = v + db[0];
}

// ---------------------------------------------------------------------------
// Fallback (ws too small): round-1 passing implementation.
// ---------------------------------------------------------------------------
__global__ __launch_bounds__(256, 2) void ecc_edge_slow(
    const float* __restrict__ x, const float* __restrict__ ef,
    const int* __restrict__ src, const int* __restrict__ dst,
    const float* __restrict__ W, const float* __restrict__ B,
    float* __restrict__ agg, int E)
{
    const int tid = blockIdx.x * blockDim.x + threadIdx.x;
    const bool live = (tid < E);
    const int e = live ? tid : (E - 1);
    const int sn = src[e], dn = dst[e];
    float xr[F];
    const float4* xp = (const float4*)(x + (size_t)sn * F);
    #pragma unroll
    for (int i = 0; i < F / 4; ++i) {
        float4 v = xp[i];
        xr[4*i+0] = v.x; xr[4*i+1] = v.y; xr[4*i+2] = v.z; xr[4*i+3] = v.w;
    }
    float acc[F];
    #pragma unroll
    for (int o = 0; o < F; ++o) acc[o] = 0.0f;
    const float* erow = ef + (size_t)e * S;
    for (int s = 0; s < S; ++s) {
        const float es = erow[s];
        const float* Ws = W + s * (F * F);
        #pragma unroll
        for (int f = 0; f < F; ++f) {
            const float z = es * xr[f];
            #pragma unroll
            for (int o = 0; o < F; ++o) acc[o] = fmaf(z, Ws[f * F + o], acc[o]);
        }
    }
    #pragma unroll
    for (int f = 0; f < F; ++f) {
        const float xf = xr[f];
        #pragma unroll
        for (int o = 0; o < F; ++o) acc[o] = fmaf(xf, B[f * F + o], acc[o]);
    }
    if (live) {
        float* ap = agg + (size_t)dn * F;
        #pragma unroll
        for (int o = 0; o < F; ++o) atomicAdd(ap + o, acc[o]);
    }
}

__global__ __launch_bounds__(256) void ecc_node_slow(
    const float* __restrict__ xin, const float* __restrict__ root,
    const float* __restrict__ bias, float* __restrict__ h, int N)
{
    int t = blockIdx.x * blockDim.x + threadIdx.x;
    if (t >= N * F) return;
    const int n = t >> 5, o = t & (F - 1);
    const float* xrow = xin + (size_t)n * F;
    float v = h[t] + bias[o];
    #pragma unroll
    for (int f = 0; f < F; ++f) v = fmaf(xrow[f], root[f * F + o], v);
    h[t] = fmaxf(v, 0.0f);
}

// ---------------------------------------------------------------------------
extern "C" void kernel_launch(void* const* d_in, const int* in_sizes, int n_in,
                              void* d_out, int out_size, void* d_ws, size_t ws_size,
                              hipStream_t stream) {
    const float* x      = (const float*)d_in[0];
    const float* efeat  = (const float*)d_in[1];
    const int*   src    = (const int*)d_in[2];
    const int*   dst    = (const int*)d_in[3];
    const float* fgn_w1 = (const float*)d_in[4];
    const float* fgn_b1 = (const float*)d_in[5];
    const float* root1  = (const float*)d_in[6];
    const float* bias1  = (const float*)d_in[7];
    const float* fgn_w2 = (const float*)d_in[8];
    const float* fgn_b2 = (const float*)d_in[9];
    const float* root2  = (const float*)d_in[10];
    const float* bias2  = (const float*)d_in[11];
    const float* dense_w = (const float*)d_in[12];
    const float* dense_b = (const float*)d_in[13];

    const int N = in_sizes[0] / F;
    const int E = in_sizes[2];

    const size_t Ybytes   = (size_t)N * J * 2;           // bf16 Y
    const size_t aggBytes = (size_t)N * F * sizeof(float);
    const size_t wbtBytes = (size_t)J * F * 2;           // 36864 B each
    const size_t need     = Ybytes + 2 * aggBytes + 128 + 2 * wbtBytes + 256;

    if (ws_size >= need) {
        unsigned*       Yu = (unsigned*)d_ws;
        unsigned short* Yb = (unsigned short*)d_ws;
        float* agg1   = (float*)((char*)d_ws + Ybytes);
        float* agg2   = agg1 + (size_t)N * F;
        float* pooled = agg2 + (size_t)N * F;
        unsigned short* Wbt1 = (unsigned short*)((char*)d_ws + Ybytes + 2 * aggBytes + 128);
        unsigned short* Wbt2 = Wbt1 + J * F;

        hipMemsetAsync((char*)d_ws + Ybytes, 0, 2 * aggBytes + F * sizeof(float), stream);

        convert_w<<<(2 * J * F + 255) / 256, 256, 0, stream>>>(
            fgn_w1, fgn_b1, root1, fgn_w2, fgn_b2, root2, Wbt1, Wbt2);

        const int gemmBlocks = (N + 63) / 64;
        const int edgeBlocks = (E * (F / 2) + 255) / 256;
        const int nodeBlocks = (N * F + 255) / 256;

        // ---- layer 1 ----
        y_gemm<<<gemmBlocks, 256, 0, stream>>>(x, Wbt1, Yb, N);
        edge_gather<<<edgeBlocks, 256, 0, stream>>>(Yu, efeat, src, dst, agg1, E);
        node_fuse<<<nodeBlocks, 256, 0, stream>>>(Yb, bias1, agg1, N);  // agg1 -> h1

        // ---- layer 2 ----
        y_gemm<<<gemmBlocks, 256, 0, stream>>>(agg1, Wbt2, Yb, N);
        edge_gather<<<edgeBlocks, 256, 0, stream>>>(Yu, efeat, src, dst, agg2, E);
        node_fuse<<<nodeBlocks, 256, 0, stream>>>(Yb, bias2, agg2, N);  // agg2 -> h2

        pool_kernel<<<512, 256, 0, stream>>>(agg2, pooled, N);
        final_kernel<<<1, 64, 0, stream>>>(pooled, dense_w, dense_b, (float*)d_out);
    } else {
        // fallback: round-1 passing path
        float* agg1   = (float*)d_ws;
        float* agg2   = agg1 + (size_t)N * F;
        float* pooled = agg2 + (size_t)N * F;
        hipMemsetAsync(d_ws, 0, 2 * aggBytes + F * sizeof(float), stream);
        const int edgeBlocks = (E + 255) / 256;
        const int nodeBlocks = (N * F + 255) / 256;
        ecc_edge_slow<<<edgeBlocks, 256, 0, stream>>>(x, efeat, src, dst, fgn_w1, fgn_b1, agg1, E);
        ecc_node_slow<<<nodeBlocks, 256, 0, stream>>>(x, root1, bias1, agg1, N);
        ecc_edge_slow<<<edgeBlocks, 256, 0, stream>>>(agg1, efeat, src, dst, fgn_w2, fgn_b2, agg2, E);
        ecc_node_slow<<<nodeBlocks, 256, 0, stream>>>(agg1, root2, bias2, agg2, N);
        pool_kernel<<<512, 256, 0, stream>>>(agg2, pooled, N);
        final_kernel<<<1, 64, 0, stream>>>(pooled, dense_w, dense_b, (float*)d_out);
    }
}